// Round 4
// baseline (44.873 us; speedup 1.0000x reference)
//
#include <hip/hip_runtime.h>
#include <hip/hip_bf16.h>

// Binary-quantization entropy per row, two-stage, nontemporal streaming reads.
// values: [B=256, N=262144] fp32. c1 = #positives per row, c0 = N - c1,
// p = c / (N + 1e-8), H = -sum(p * log2(p + 1e-10)) over bins with p > 0.
//
// Stage 1: 2048 blocks x 256 threads (8 blocks/CU -> 32 waves/CU resident),
//          each block counts positives in one contiguous 1/8-row slice via
//          nontemporal float4 loads (268 MB thrashes the 256 MB L3 anyway;
//          nt skips the useless cache fill). One int partial per block to
//          d_ws. No atomics, deterministic.
// Stage 2: 1 block x 256 threads; thread r sums its row's 8 partials and
//          computes the 2-bin entropy.

#define B_ROWS 256
#define N_PER_ROW 262144
#define SLICES 8
#define SLICE_ELEMS (N_PER_ROW / SLICES)      // 32768 floats = 8192 float4
#define BLOCK_THREADS 256
#define WAVES_PER_BLOCK (BLOCK_THREADS / 64)  // 4
#define ITERS (SLICE_ELEMS / 4 / BLOCK_THREADS)  // 32 float4 per thread

// Native clang vector type — __builtin_nontemporal_load requires this
// (HIP_vector_type float4 is a struct and is rejected).
typedef float floatx4 __attribute__((ext_vector_type(4)));

__global__ __launch_bounds__(BLOCK_THREADS) void count_slices_kernel(
    const float* __restrict__ values, int* __restrict__ partial) {
  const int blk = blockIdx.x;          // 0..2047
  const int row = blk >> 3;
  const int slice = blk & (SLICES - 1);
  const int tid = threadIdx.x;

  const floatx4* p = reinterpret_cast<const floatx4*>(
      values + (size_t)row * N_PER_ROW + (size_t)slice * SLICE_ELEMS);

  int c = 0;
#pragma unroll 8
  for (int i = 0; i < ITERS; ++i) {
    floatx4 v = __builtin_nontemporal_load(&p[i * BLOCK_THREADS + tid]);
    c += (v.x > 0.0f) + (v.y > 0.0f) + (v.z > 0.0f) + (v.w > 0.0f);
  }

  // 64-lane wave reduction
#pragma unroll
  for (int off = 32; off > 0; off >>= 1) c += __shfl_down(c, off, 64);

  __shared__ int wsum[WAVES_PER_BLOCK];
  const int lane = tid & 63;
  const int wave = tid >> 6;
  if (lane == 0) wsum[wave] = c;
  __syncthreads();

  if (tid == 0) {
    int s = wsum[0];
#pragma unroll
    for (int w = 1; w < WAVES_PER_BLOCK; ++w) s += wsum[w];
    partial[blk] = s;
  }
}

__global__ __launch_bounds__(B_ROWS) void entropy_finalize_kernel(
    const int* __restrict__ partial, float* __restrict__ out) {
  const int row = threadIdx.x;  // 0..255
  int c1 = 0;
#pragma unroll
  for (int s = 0; s < SLICES; ++s) c1 += partial[row * SLICES + s];
  const int c0 = N_PER_ROW - c1;
  // n + 1e-8 rounds to n in fp32, matching jnp's fp32 math.
  const float inv_n = 1.0f / (float)N_PER_ROW;
  const float p0 = (float)c0 * inv_n;
  const float p1 = (float)c1 * inv_n;
  const float t0 = (p0 > 0.0f) ? p0 * log2f(p0 + 1e-10f) : 0.0f;
  const float t1 = (p1 > 0.0f) ? p1 * log2f(p1 + 1e-10f) : 0.0f;
  out[row] = -(t0 + t1);
}

extern "C" void kernel_launch(void* const* d_in, const int* in_sizes, int n_in,
                              void* d_out, int out_size, void* d_ws, size_t ws_size,
                              hipStream_t stream) {
  const float* values = (const float*)d_in[0];
  float* out = (float*)d_out;
  int* partial = (int*)d_ws;  // 2048 ints = 8 KB, all slots written by stage 1

  count_slices_kernel<<<B_ROWS * SLICES, BLOCK_THREADS, 0, stream>>>(values, partial);
  entropy_finalize_kernel<<<1, B_ROWS, 0, stream>>>(partial, out);
}